// Round 3
// baseline (90.253 us; speedup 1.0000x reference)
//
#include <hip/hip_runtime.h>

// MaskCostVolumeLoss: scalar = sum(w * min_shift(mean_c |pred - target_shift|)) / sum(w)
// over interior pixels only (2-px border masked). N=4, C=3, H=W=512, K=5, P=2.
// R3: 2 pixels/thread -> 2017 blocks (~31.5 waves/CU) to deepen the VMEM pipeline;
// channel-inner loop keeps live set ~45 VGPR so launch_bounds(256,8) holds.

#define KK 5
#define PP 2
#define NN 4
#define CC 3
#define HH 512
#define WW 512
#define HI 508            // interior rows (y = 2..509)
#define WI2 254           // interior cols / 2 (x0 = 2 + 2*px, px in [0,254))
#define TOTAL (NN * HI * WI2)          // 516,128 pixel-pairs
#define NBLK ((TOTAL + 255) / 256)     // 2017 blocks

__global__ __launch_bounds__(256, 8) void cvloss_main(
    const float* __restrict__ pred,
    const float* __restrict__ target,
    const float* __restrict__ weight,
    float2* __restrict__ partials)     // partials[b] = {num, den}
{
    const int tid = blockIdx.x * 256 + threadIdx.x;

    float num = 0.f, den = 0.f;

    if (tid < TOTAL) {
        const int px   = tid % WI2;
        const int rest = tid / WI2;
        const int y    = rest % HI + PP;
        const int n    = rest / HI;
        const int x0   = 2 * px + PP;          // x0 - PP = 2*px -> 8B aligned

        const size_t plane = (size_t)HH * WW;
        const float* pn = pred   + (size_t)n * CC * plane;
        const float* tn = target + (size_t)n * CC * plane;

        // pred: 3 channels x 2 pixels
        float p[3][2];
        #pragma unroll
        for (int c = 0; c < 3; ++c) {
            float2 a = *(const float2*)(pn + c * plane + (size_t)y * WW + x0);
            p[c][0] = a.x; p[c][1] = a.y;
        }

        float mn0 = 1e30f, mn1 = 1e30f;

        #pragma unroll
        for (int dy = 0; dy < KK; ++dy) {
            const size_t rowoff = (size_t)(y + dy - PP) * WW + (x0 - PP);
            float acc[KK][2];
            #pragma unroll
            for (int c = 0; c < 3; ++c) {
                const float* r = tn + c * plane + rowoff;
                // 6 floats covering x0-2 .. x0+3, three 8B-aligned float2 loads
                float2 a = *(const float2*)(r);
                float2 b = *(const float2*)(r + 2);
                float2 d = *(const float2*)(r + 4);
                float t6[6] = {a.x, a.y, b.x, b.y, d.x, d.y};
                #pragma unroll
                for (int dx = 0; dx < KK; ++dx) {
                    float d0 = fabsf(p[c][0] - t6[dx]);
                    float d1 = fabsf(p[c][1] - t6[dx + 1]);
                    if (c == 0) { acc[dx][0] = d0;  acc[dx][1] = d1; }
                    else        { acc[dx][0] += d0; acc[dx][1] += d1; }
                }
            }
            #pragma unroll
            for (int dx = 0; dx < KK; ++dx) {
                mn0 = fminf(mn0, acc[dx][0]);
                mn1 = fminf(mn1, acc[dx][1]);
            }
        }

        float2 w = *(const float2*)(weight + (size_t)n * CC * plane
                                    + (size_t)y * WW + x0);
        num = (w.x * mn0 + w.y * mn1) * (1.f / 3.f);   // mean over channels
        den = w.x + w.y;
    }

    // wave (64-lane) shuffle reduction
    #pragma unroll
    for (int o = 32; o > 0; o >>= 1) {
        num += __shfl_down(num, o);
        den += __shfl_down(den, o);
    }

    __shared__ float snum[4], sden[4];
    const int lane = threadIdx.x & 63;
    const int wv   = threadIdx.x >> 6;
    if (lane == 0) { snum[wv] = num; sden[wv] = den; }
    __syncthreads();
    if (threadIdx.x == 0) {
        float2 out;
        out.x = snum[0] + snum[1] + snum[2] + snum[3];
        out.y = sden[0] + sden[1] + sden[2] + sden[3];
        partials[blockIdx.x] = out;   // plain write: no zero-init needed
    }
}

__global__ __launch_bounds__(256) void cvloss_reduce(
    const float2* __restrict__ partials, float* __restrict__ out)
{
    const int t = threadIdx.x;
    float num = 0.f, den = 0.f;
    for (int i = t; i < NBLK; i += 256) {
        float2 a = partials[i];
        num += a.x;
        den += a.y;
    }

    #pragma unroll
    for (int o = 32; o > 0; o >>= 1) {
        num += __shfl_down(num, o);
        den += __shfl_down(den, o);
    }

    __shared__ float snum[4], sden[4];
    const int lane = t & 63;
    const int wv   = t >> 6;
    if (lane == 0) { snum[wv] = num; sden[wv] = den; }
    __syncthreads();
    if (t == 0) {
        float bn = snum[0] + snum[1] + snum[2] + snum[3];
        float bd = sden[0] + sden[1] + sden[2] + sden[3];
        out[0] = bn / bd;
    }
}

extern "C" void kernel_launch(void* const* d_in, const int* in_sizes, int n_in,
                              void* d_out, int out_size, void* d_ws, size_t ws_size,
                              hipStream_t stream) {
    const float* pred   = (const float*)d_in[0];
    const float* target = (const float*)d_in[1];
    const float* weight = (const float*)d_in[2];
    float* out = (float*)d_out;
    float2* partials = (float2*)d_ws;

    cvloss_main<<<NBLK, 256, 0, stream>>>(pred, target, weight, partials);
    cvloss_reduce<<<1, 256, 0, stream>>>(partials, out);
}

// Round 4
// 85.086 us; speedup vs baseline: 1.0607x; 1.0607x over previous
//
#include <hip/hip_runtime.h>

// MaskCostVolumeLoss: scalar = sum(w * min_shift(mean_c |pred - target_shift|)) / sum(w)
// over interior pixels (2-px border masked). N=4, C=3, H=W=512, K=5, P=2.
// R4: LDS-strip kernel. Each block = (n, 4-row strip); target rows y0-2..y0+5
// x 3ch staged to LDS via async global_load_lds dwordx4 (fire-and-forget ->
// unlimited outstanding, no VGPR dests). Compute reads target from LDS as
// float4; pred/weight direct float2 loads (read-once).

#define KK 5
#define PP 2
#define NN 4
#define CC 3
#define HH 512
#define WW 512
#define RSTRIP 4                  // interior rows per block
#define NSTRIP 127                // strips per image (508/4)
#define NBLK (NN * NSTRIP)        // 508 blocks
#define SROWS (RSTRIP + KK - 1)   // 8 staged rows per channel
#define LDS_FLOATS (CC * SROWS * WW)   // 12288 floats = 48 KB

__device__ __forceinline__ void async_load16(const float* g, float* l) {
    __builtin_amdgcn_global_load_lds(
        (const __attribute__((address_space(1))) void*)g,
        (__attribute__((address_space(3))) void*)l, 16, 0, 0);
}

__global__ __launch_bounds__(256, 2) void cvloss_main(
    const float* __restrict__ pred,
    const float* __restrict__ target,
    const float* __restrict__ weight,
    float2* __restrict__ partials)     // partials[b] = {num, den}
{
    __shared__ float tlds[LDS_FLOATS];

    const int n     = blockIdx.x / NSTRIP;
    const int strip = blockIdx.x % NSTRIP;
    const int y0    = PP + strip * RSTRIP;        // first interior row of strip
    const int tid   = threadIdx.x;

    const size_t plane = (size_t)HH * WW;
    const float* tn = target + (size_t)n * CC * plane;
    const float* pn = pred   + (size_t)n * CC * plane;

    // ---- stage: 3 channels x 8 rows x 512 floats, 4KB rounds ----
    // round (c, r): global floats [(y0-2)*512 + r*1024 .. +1024) of channel c
    //   -> lds [c*4096 + r*1024 .. +1024)
    // thread tid moves 16B at element offset tid*4; LDS dst base must be
    // wave-uniform (hw adds lane*16B).
    {
        const float* gbase = tn + (size_t)(y0 - PP) * WW;
        const int woff = (tid >> 6) << 8;          // wave base in floats (w*256)
        const int loff = (tid & 63) ? 0 : 0;       // (lane offset added by HW)
        (void)loff;
        #pragma unroll
        for (int c = 0; c < CC; ++c) {
            #pragma unroll
            for (int r = 0; r < 4; ++r) {
                const float* g = gbase + c * plane + (size_t)r * 1024 + (size_t)tid * 4;
                float* l = &tlds[c * (SROWS * WW) + r * 1024 + woff];
                async_load16(g, l);
            }
        }
    }

    // ---- independent global loads (don't depend on LDS) ----
    // thread t handles quads q0 = t, q1 = t + 256 (quad = 4 px; 508 quads/block)
    const int q0 = tid;
    const int q1 = tid + 256;

    float p0[3][4], p1[3][4];
    float w0[4] = {0, 0, 0, 0}, w1[4] = {0, 0, 0, 0};

    const int r0 = q0 / NSTRIP, tx0 = q0 % NSTRIP;
    const int r1 = q1 / NSTRIP, tx1 = q1 % NSTRIP;
    const int x0 = PP + 4 * tx0;
    const int x1 = PP + 4 * tx1;
    const bool v1 = (q1 < RSTRIP * NSTRIP);

    #pragma unroll
    for (int c = 0; c < 3; ++c) {
        const float* base0 = pn + c * plane + (size_t)(y0 + r0) * WW + x0;
        float2 a = *(const float2*)(base0), b = *(const float2*)(base0 + 2);
        p0[c][0] = a.x; p0[c][1] = a.y; p0[c][2] = b.x; p0[c][3] = b.y;
        if (v1) {
            const float* base1 = pn + c * plane + (size_t)(y0 + r1) * WW + x1;
            float2 d = *(const float2*)(base1), e = *(const float2*)(base1 + 2);
            p1[c][0] = d.x; p1[c][1] = d.y; p1[c][2] = e.x; p1[c][3] = e.y;
        }
    }
    {
        const float* wn = weight + (size_t)n * CC * plane;
        const float* wb0 = wn + (size_t)(y0 + r0) * WW + x0;
        float2 a = *(const float2*)(wb0), b = *(const float2*)(wb0 + 2);
        w0[0] = a.x; w0[1] = a.y; w0[2] = b.x; w0[3] = b.y;
        if (v1) {
            const float* wb1 = wn + (size_t)(y0 + r1) * WW + x1;
            float2 d = *(const float2*)(wb1), e = *(const float2*)(wb1 + 2);
            w1[0] = d.x; w1[1] = d.y; w1[2] = e.x; w1[3] = e.y;
        }
    }

    __syncthreads();   // drains vmcnt (stage complete) + barrier

    // ---- compute from LDS ----
    float num = 0.f, den = 0.f;

    // quad 0
    {
        float mn[4] = {1e30f, 1e30f, 1e30f, 1e30f};
        #pragma unroll
        for (int dy = 0; dy < KK; ++dy) {
            float acc[KK][4];
            #pragma unroll
            for (int c = 0; c < 3; ++c) {
                const float* lrow = &tlds[c * (SROWS * WW) + (r0 + dy) * WW + (x0 - PP)];
                float4 A = *(const float4*)(lrow);
                float4 B = *(const float4*)(lrow + 4);
                float t8[8] = {A.x, A.y, A.z, A.w, B.x, B.y, B.z, B.w};
                #pragma unroll
                for (int dx = 0; dx < KK; ++dx) {
                    #pragma unroll
                    for (int j = 0; j < 4; ++j) {
                        float d = fabsf(p0[c][j] - t8[dx + j]);
                        if (c == 0) acc[dx][j] = d; else acc[dx][j] += d;
                    }
                }
            }
            #pragma unroll
            for (int dx = 0; dx < KK; ++dx)
                #pragma unroll
                for (int j = 0; j < 4; ++j)
                    mn[j] = fminf(mn[j], acc[dx][j]);
        }
        #pragma unroll
        for (int j = 0; j < 4; ++j) {
            num += w0[j] * mn[j];
            den += w0[j];
        }
    }

    // quad 1
    if (v1) {
        float mn[4] = {1e30f, 1e30f, 1e30f, 1e30f};
        #pragma unroll
        for (int dy = 0; dy < KK; ++dy) {
            float acc[KK][4];
            #pragma unroll
            for (int c = 0; c < 3; ++c) {
                const float* lrow = &tlds[c * (SROWS * WW) + (r1 + dy) * WW + (x1 - PP)];
                float4 A = *(const float4*)(lrow);
                float4 B = *(const float4*)(lrow + 4);
                float t8[8] = {A.x, A.y, A.z, A.w, B.x, B.y, B.z, B.w};
                #pragma unroll
                for (int dx = 0; dx < KK; ++dx) {
                    #pragma unroll
                    for (int j = 0; j < 4; ++j) {
                        float d = fabsf(p1[c][j] - t8[dx + j]);
                        if (c == 0) acc[dx][j] = d; else acc[dx][j] += d;
                    }
                }
            }
            #pragma unroll
            for (int dx = 0; dx < KK; ++dx)
                #pragma unroll
                for (int j = 0; j < 4; ++j)
                    mn[j] = fminf(mn[j], acc[dx][j]);
        }
        #pragma unroll
        for (int j = 0; j < 4; ++j) {
            num += w1[j] * mn[j];
            den += w1[j];
        }
    }

    num *= (1.f / 3.f);   // mean over channels

    // wave (64-lane) shuffle reduction
    #pragma unroll
    for (int o = 32; o > 0; o >>= 1) {
        num += __shfl_down(num, o);
        den += __shfl_down(den, o);
    }

    __shared__ float snum[4], sden[4];
    const int lane = threadIdx.x & 63;
    const int wv   = threadIdx.x >> 6;
    if (lane == 0) { snum[wv] = num; sden[wv] = den; }
    __syncthreads();
    if (threadIdx.x == 0) {
        float2 out;
        out.x = snum[0] + snum[1] + snum[2] + snum[3];
        out.y = sden[0] + sden[1] + sden[2] + sden[3];
        partials[blockIdx.x] = out;   // plain write: no zero-init needed
    }
}

__global__ __launch_bounds__(256) void cvloss_reduce(
    const float2* __restrict__ partials, float* __restrict__ out)
{
    const int t = threadIdx.x;
    float num = 0.f, den = 0.f;
    for (int i = t; i < NBLK; i += 256) {
        float2 a = partials[i];
        num += a.x;
        den += a.y;
    }

    #pragma unroll
    for (int o = 32; o > 0; o >>= 1) {
        num += __shfl_down(num, o);
        den += __shfl_down(den, o);
    }

    __shared__ float snum[4], sden[4];
    const int lane = t & 63;
    const int wv   = t >> 6;
    if (lane == 0) { snum[wv] = num; sden[wv] = den; }
    __syncthreads();
    if (t == 0) {
        float bn = snum[0] + snum[1] + snum[2] + snum[3];
        float bd = sden[0] + sden[1] + sden[2] + sden[3];
        out[0] = bn / bd;
    }
}

extern "C" void kernel_launch(void* const* d_in, const int* in_sizes, int n_in,
                              void* d_out, int out_size, void* d_ws, size_t ws_size,
                              hipStream_t stream) {
    const float* pred   = (const float*)d_in[0];
    const float* target = (const float*)d_in[1];
    const float* weight = (const float*)d_in[2];
    float* out = (float*)d_out;
    float2* partials = (float2*)d_ws;

    cvloss_main<<<NBLK, 256, 0, stream>>>(pred, target, weight, partials);
    cvloss_reduce<<<1, 256, 0, stream>>>(partials, out);
}